// Round 1
// baseline (731.988 us; speedup 1.0000x reference)
//
#include <hip/hip_runtime.h>
#include <stdint.h>

#define BB 4
#define HH 512
#define WW 512
#define HWW (HH*WW)      // 262144 = 1<<18
#define CC 128
#define KK 512
#define RR 3
#define CAP 32768
#define SELCAP 2048

// ---------------- separable 7x7 pooling helpers ----------------

__device__ __forceinline__ float colmax7f(const float* __restrict__ p, int g){
    int y = (g >> 9) & (HH - 1);
    float m = -1e30f;
#pragma unroll
    for (int d = -RR; d <= RR; ++d){
        int yy = y + d;
        if (yy >= 0 && yy < HH) m = fmaxf(m, p[g + d * WW]);
    }
    return m;
}

__global__ void rowmax_k(const float* __restrict__ in, float* __restrict__ out){
    int g = blockIdx.x * blockDim.x + threadIdx.x;
    if (g >= BB * HWW) return;
    int x = g & (WW - 1);
    float m = -1e30f;
#pragma unroll
    for (int d = -RR; d <= RR; ++d){
        int xx = x + d;
        if (xx >= 0 && xx < WW) m = fmaxf(m, in[g + d]);
    }
    out[g] = m;
}

// M0 = (s == maxpool7(s))
__global__ void m0_k(const float* __restrict__ rm, const float* __restrict__ s,
                     unsigned char* __restrict__ M){
    int g = blockIdx.x * blockDim.x + threadIdx.x;
    if (g >= BB * HWW) return;
    M[g] = (s[g] == colmax7f(rm, g)) ? 1 : 0;
}

// row OR of mask
__global__ void rowor_k(const unsigned char* __restrict__ in, unsigned char* __restrict__ out){
    int g = blockIdx.x * blockDim.x + threadIdx.x;
    if (g >= BB * HWW) return;
    int x = g & (WW - 1);
    unsigned char v = 0;
#pragma unroll
    for (int d = -RR; d <= RR; ++d){
        int xx = x + d;
        if (xx >= 0 && xx < WW) v |= in[g + d];
    }
    out[g] = v;
}

// supp = col OR (dilated mask); ss = supp ? 0 : s
__global__ void color_ss_k(const unsigned char* __restrict__ t, const float* __restrict__ s,
                           unsigned char* __restrict__ supp, float* __restrict__ ss){
    int g = blockIdx.x * blockDim.x + threadIdx.x;
    if (g >= BB * HWW) return;
    int y = (g >> 9) & (HH - 1);
    unsigned char v = 0;
#pragma unroll
    for (int d = -RR; d <= RR; ++d){
        int yy = y + d;
        if (yy >= 0 && yy < HH) v |= t[g + d * WW];
    }
    supp[g] = v;
    ss[g] = v ? 0.0f : s[g];
}

// M |= (ss == maxpool7(ss)) & ~supp
__global__ void update_k(const float* __restrict__ rm, const float* __restrict__ ss,
                         const unsigned char* __restrict__ supp, unsigned char* __restrict__ M){
    int g = blockIdx.x * blockDim.x + threadIdx.x;
    if (g >= BB * HWW) return;
    bool nm = (ss[g] == colmax7f(rm, g));
    if (nm && !supp[g]) M[g] = 1;
}

// final mask and candidate compaction
__global__ void final_k(const float* __restrict__ rm, const float* __restrict__ ss,
                        const unsigned char* __restrict__ supp, const unsigned char* __restrict__ M,
                        const float* __restrict__ s,
                        float* __restrict__ cs, int* __restrict__ ci, int* __restrict__ cnt){
    int g = blockIdx.x * blockDim.x + threadIdx.x;
    if (g >= BB * HWW) return;
    bool nm = (ss[g] == colmax7f(rm, g));
    bool m2 = M[g] || (nm && !supp[g]);
    float sv = s[g];
    if (m2 && sv > 0.0f){
        int b = g >> 18;
        int p = atomicAdd(&cnt[b], 1);
        if (p < CAP){
            cs[b * CAP + p] = sv;
            ci[b * CAP + p] = g & (HWW - 1);
        }
    }
}

// ---------------- per-batch top-K + gather ----------------

__global__ __launch_bounds__(256) void finalize_k(
        const float* __restrict__ cs, const int* __restrict__ ci, const int* __restrict__ cnt,
        const float* __restrict__ points, const float* __restrict__ feat,
        float* __restrict__ out){
    __shared__ int hist[256];
    __shared__ unsigned long long keys[SELCAP];
    __shared__ int sidx[KK];
    __shared__ unsigned int sh_prefix;
    __shared__ int sh_kneed;
    __shared__ int selCnt;

    int b = blockIdx.x, tid = threadIdx.x;
    const float* bs = cs + b * CAP;
    const int*   bi = ci + b * CAP;
    int n = cnt[b]; if (n > CAP) n = CAP;

    // exact K-th largest via 4x8-bit radix select on float bits (all scores > 0)
    unsigned int Tbits = 1u;
    if (n >= KK){
        unsigned int prefix = 0; int kneed = KK;
        for (int r = 0; r < 4; ++r){
            int shift = 24 - 8 * r;
            for (int i = tid; i < 256; i += blockDim.x) hist[i] = 0;
            __syncthreads();
            for (int i = tid; i < n; i += blockDim.x){
                unsigned int bits = __float_as_uint(bs[i]);
                if (r == 0 || (bits >> (shift + 8)) == prefix)
                    atomicAdd(&hist[(bits >> shift) & 255], 1);
            }
            __syncthreads();
            if (tid == 0){
                int cum = 0, d = 255;
                for (; d >= 0; --d){ cum += hist[d]; if (cum >= kneed) break; }
                if (d < 0) d = 0; // cannot happen when n>=K
                sh_kneed = kneed - (cum - hist[d]);
                sh_prefix = (prefix << 8) | (unsigned int)d;
            }
            __syncthreads();
            prefix = sh_prefix; kneed = sh_kneed;
            __syncthreads();
        }
        Tbits = prefix;
    }

    // collect all candidates with score >= T
    if (tid == 0) selCnt = 0;
    __syncthreads();
    for (int i = tid; i < n; i += blockDim.x){
        unsigned int bits = __float_as_uint(bs[i]);
        if (bits >= Tbits){
            int p = atomicAdd(&selCnt, 1);
            if (p < SELCAP)
                keys[p] = ((unsigned long long)bits << 32) | (unsigned int)(~bi[i]);
        }
    }
    __syncthreads();
    int ns = selCnt; if (ns > SELCAP) ns = SELCAP;
    int P = 2; while (P < ns) P <<= 1;
    for (int i = tid; i < P; i += blockDim.x) if (i >= ns) keys[i] = 0ull;
    __syncthreads();

    // bitonic sort descending by (score_bits, ~idx)  => score desc, idx asc
    for (int k = 2; k <= P; k <<= 1){
        for (int j = k >> 1; j > 0; j >>= 1){
            for (int i = tid; i < P; i += blockDim.x){
                int partner = i ^ j;
                if (partner > i){
                    unsigned long long a = keys[i], c = keys[partner];
                    bool asc = ((i & k) != 0);
                    if ((a < c) != asc){ keys[i] = c; keys[partner] = a; }
                }
            }
            __syncthreads();
        }
    }

    for (int k = tid; k < KK; k += blockDim.x){
        int idx = -1;
        if (k < ns) idx = (int)(~(unsigned int)(keys[k] & 0xFFFFFFFFull));
        sidx[k] = idx;
    }
    __syncthreads();
    if (ns < KK && tid == 0){
        // fallback (unreachable with real data): fill with smallest non-candidate indices
        int fill = ns;
        for (int idx = 0; idx < HWW && fill < KK; ++idx){
            bool inCand = false;
            for (int i = 0; i < n; ++i) if (bi[i] == idx){ inCand = true; break; }
            if (!inCand) sidx[fill++] = idx;
        }
    }
    __syncthreads();

    // outputs: kpts (B,K,4) | feas (B,C,K) | pixels (B,K,2)
    const float* pb = points + (size_t)b * 4 * HWW;
    float* out0 = out + (size_t)b * KK * 4;
    float* out2 = out + (size_t)(BB * KK * 4 + BB * CC * KK) + (size_t)b * KK * 2;
    for (int k = tid; k < KK; k += blockDim.x){
        int idx = sidx[k];
        out0[k * 4 + 0] = pb[idx];
        out0[k * 4 + 1] = pb[HWW + idx];
        out0[k * 4 + 2] = 0.0f;
        out0[k * 4 + 3] = 1.0f;
        out2[k * 2 + 0] = (float)(idx >> 9);       // u = idx // W
        out2[k * 2 + 1] = (float)(idx & (WW - 1)); // v = idx % W
    }
    const float* fb = feat + (size_t)b * CC * HWW;
    float* out1 = out + (size_t)(BB * KK * 4) + (size_t)b * CC * KK;
    for (int j = tid; j < CC * KK; j += blockDim.x){
        int c = j >> 9;          // KK = 512
        int k = j & (KK - 1);
        out1[c * KK + k] = fb[(size_t)c * HWW + sidx[k]];
    }
}

extern "C" void kernel_launch(void* const* d_in, const int* in_sizes, int n_in,
                              void* d_out, int out_size, void* d_ws, size_t ws_size,
                              hipStream_t stream) {
    const float* s    = (const float*)d_in[0];  // score_bev  (B,1,H,W)
    const float* feat = (const float*)d_in[1];  // feature_bev(B,C,H,W)
    const float* pts  = (const float*)d_in[2];  // points     (B,4,H,W)
    float* out = (float*)d_out;

    char* w = (char*)d_ws;
    float* tf  = (float*)w;          w += (size_t)BB * HWW * 4;
    float* ssf = (float*)w;          w += (size_t)BB * HWW * 4;
    unsigned char* M    = (unsigned char*)w; w += (size_t)BB * HWW;
    unsigned char* supp = (unsigned char*)w; w += (size_t)BB * HWW;
    unsigned char* t1   = (unsigned char*)w; w += (size_t)BB * HWW;
    float* cs = (float*)w;           w += (size_t)BB * CAP * 4;
    int*   ci = (int*)w;             w += (size_t)BB * CAP * 4;
    int*   cnt = (int*)w;            w += 256;

    hipMemsetAsync(cnt, 0, BB * sizeof(int), stream);

    const int nthr = 256;
    const int nblk = (BB * HWW) / nthr;

    // M0 = (s == pool7(s))
    rowmax_k<<<nblk, nthr, 0, stream>>>(s, tf);
    m0_k    <<<nblk, nthr, 0, stream>>>(tf, s, M);
    // iter 1
    rowor_k   <<<nblk, nthr, 0, stream>>>(M, t1);
    color_ss_k<<<nblk, nthr, 0, stream>>>(t1, s, supp, ssf);
    rowmax_k  <<<nblk, nthr, 0, stream>>>(ssf, tf);
    update_k  <<<nblk, nthr, 0, stream>>>(tf, ssf, supp, M);
    // iter 2
    rowor_k   <<<nblk, nthr, 0, stream>>>(M, t1);
    color_ss_k<<<nblk, nthr, 0, stream>>>(t1, s, supp, ssf);
    rowmax_k  <<<nblk, nthr, 0, stream>>>(ssf, tf);
    final_k   <<<nblk, nthr, 0, stream>>>(tf, ssf, supp, M, s, cs, ci, cnt);
    // top-K + gathers
    finalize_k<<<BB, 256, 0, stream>>>(cs, ci, cnt, pts, feat, out);
}

// Round 2
// 219.483 us; speedup vs baseline: 3.3351x; 3.3351x over previous
//
#include <hip/hip_runtime.h>
#include <stdint.h>
#include <math.h>

#define BB 4
#define HH 512
#define WW 512
#define HWW (HH*WW)      // 262144
#define CC 128
#define KK 512
#define CAP 32768
#define SELCAP 2048

#define TILE 64
#define HALO 15
#define TS 94            // TILE + 2*HALO
#define SW 96            // padded LDS stride
#define NT 1024
#define LCAP 1024

__device__ __forceinline__ float colmax7(const float* __restrict__ p, int o){
    float m = fmaxf(fmaxf(fmaxf(p[o-3*SW], p[o-2*SW]), fmaxf(p[o-SW], p[o])),
                    fmaxf(fmaxf(p[o+SW], p[o+2*SW]), p[o+3*SW]));
    return m;
}

// One block = one 64x64 output tile (+15 halo). Entire 2-iteration NMS in LDS.
__global__ __launch_bounds__(NT) void nms_fused_k(const float* __restrict__ sc,
                                                  float* __restrict__ cs, int* __restrict__ ci,
                                                  int* __restrict__ cnt){
    __shared__ float S[TS*SW];
    __shared__ float A[TS*SW];
    __shared__ float Bf[TS*SW];
    __shared__ unsigned char M[TS*SW];
    __shared__ unsigned char T[TS*SW];
    __shared__ unsigned char P[TS*SW];
    __shared__ float lsc[LCAP];
    __shared__ int   lidx[LCAP];
    __shared__ int   lcnt;
    __shared__ int   base;

    const int tid = threadIdx.x;
    const int bb = blockIdx.x >> 6;          // batch
    const int t  = blockIdx.x & 63;
    const int ty = t >> 3, tx = t & 7;
    const int oy = ty * TILE - HALO, ox = tx * TILE - HALO;
    const float* sb = sc + (size_t)bb * HWW;

    if (tid == 0) lcnt = 0;

    // ---- load scores (out-of-image = -inf, matching reduce_window pad) ----
    for (int i = tid; i < TS*TS; i += NT){
        int y = i / TS, x = i - y * TS;
        int gy = oy + y, gx = ox + x;
        float v = -INFINITY;
        if ((unsigned)gy < (unsigned)HH && (unsigned)gx < (unsigned)WW)
            v = sb[(gy << 9) + gx];
        S[y*SW + x] = v;
    }
    __syncthreads();

#define ROWMAX(dst, src, Y0, Y1, X0, X1)                                   \
    for (int i = tid; i < (Y1-Y0)*(X1-X0); i += NT){                        \
        int y = (Y0) + i / (X1-X0), x = (X0) + i % (X1-X0);                 \
        int o = y*SW + x;                                                   \
        dst[o] = fmaxf(fmaxf(fmaxf(src[o-3],src[o-2]),fmaxf(src[o-1],src[o])), \
                       fmaxf(fmaxf(src[o+1],src[o+2]),src[o+3]));           \
    }                                                                       \
    __syncthreads();

#define ROWOR(dst, src, Y0, Y1, X0, X1)                                    \
    for (int i = tid; i < (Y1-Y0)*(X1-X0); i += NT){                        \
        int y = (Y0) + i / (X1-X0), x = (X0) + i % (X1-X0);                 \
        int o = y*SW + x;                                                   \
        dst[o] = (unsigned char)(src[o-3]|src[o-2]|src[o-1]|src[o]|         \
                                 src[o+1]|src[o+2]|src[o+3]);               \
    }                                                                       \
    __syncthreads();

// col-OR of T -> P (supp mask); A = supp ? 0 : S (out-of-image stays -inf)
#define COLSUPP(Y0, Y1)                                                     \
    for (int i = tid; i < (Y1-Y0)*(Y1-Y0); i += NT){                        \
        int y = (Y0) + i / (Y1-Y0), x = (Y0) + i % (Y1-Y0);                 \
        int o = y*SW + x;                                                   \
        unsigned char v = (unsigned char)(T[o-3*SW]|T[o-2*SW]|T[o-SW]|T[o]| \
                                          T[o+SW]|T[o+2*SW]|T[o+3*SW]);     \
        P[o] = v;                                                           \
        bool in = ((unsigned)(oy+y) < (unsigned)HH) &&                      \
                  ((unsigned)(ox+x) < (unsigned)WW);                        \
        A[o] = (!in) ? -INFINITY : (v ? 0.0f : S[o]);                       \
    }                                                                       \
    __syncthreads();

    // ---- M0 = (s == pool7(s)) ----
    ROWMAX(A, S, 0, 94, 3, 91)
    for (int i = tid; i < 88*88; i += NT){
        int y = 3 + i / 88, x = 3 + i % 88;
        int o = y*SW + x;
        float cm = colmax7(A, o);
        bool in = ((unsigned)(oy+y) < (unsigned)HH) && ((unsigned)(ox+x) < (unsigned)WW);
        M[o] = (in && S[o] == cm) ? 1 : 0;
    }
    __syncthreads();

    // ---- iteration 1 ----
    ROWOR(T, M, 3, 91, 6, 88)
    COLSUPP(6, 88)                       // P = supp1, A = ss1
    ROWMAX(Bf, A, 6, 88, 9, 85)
    for (int i = tid; i < 76*76; i += NT){   // M |= (ss==pool(ss)) & ~supp
        int y = 9 + i / 76, x = 9 + i % 76;
        int o = y*SW + x;
        float cm = colmax7(Bf, o);
        bool in = ((unsigned)(oy+y) < (unsigned)HH) && ((unsigned)(ox+x) < (unsigned)WW);
        if (in && A[o] == cm && !P[o]) M[o] = 1;
    }
    __syncthreads();

    // ---- iteration 2 ----
    ROWOR(T, M, 9, 85, 12, 82)
    COLSUPP(12, 82)                      // P = supp2, A = ss2
    ROWMAX(Bf, A, 12, 82, 15, 79)

    // ---- final mask + per-block compaction ----
    for (int i = tid; i < TILE*TILE; i += NT){
        int y = HALO + (i >> 6), x = HALO + (i & 63);
        int o = y*SW + x;
        float cm = colmax7(Bf, o);
        float sv = S[o];
        bool fm = M[o] || ((A[o] == cm) && !P[o]);
        if (fm && sv > 0.0f){
            int p = atomicAdd(&lcnt, 1);
            if (p < LCAP){ lsc[p] = sv; lidx[p] = ((oy+y) << 9) + (ox+x); }
        }
    }
    __syncthreads();
    int nl = lcnt; if (nl > LCAP) nl = LCAP;
    if (tid == 0) base = atomicAdd(&cnt[bb], nl);   // ONE global atomic per block
    __syncthreads();
    int b0 = base;
    for (int i = tid; i < nl; i += NT){
        int o = b0 + i;
        if (o < CAP){ cs[bb*CAP + o] = lsc[i]; ci[bb*CAP + o] = lidx[i]; }
    }
}

// ---------------- per-batch top-K + gather (verified round 1) ----------------

__global__ __launch_bounds__(256) void finalize_k(
        const float* __restrict__ cs, const int* __restrict__ ci, const int* __restrict__ cnt,
        const float* __restrict__ points, const float* __restrict__ feat,
        float* __restrict__ out){
    __shared__ int hist[256];
    __shared__ unsigned long long keys[SELCAP];
    __shared__ int sidx[KK];
    __shared__ unsigned int sh_prefix;
    __shared__ int sh_kneed;
    __shared__ int selCnt;

    int b = blockIdx.x, tid = threadIdx.x;
    const float* bs = cs + b * CAP;
    const int*   bi = ci + b * CAP;
    int n = cnt[b]; if (n > CAP) n = CAP;

    // exact K-th largest via 4x8-bit radix select on float bits (all scores > 0)
    unsigned int Tbits = 1u;
    if (n >= KK){
        unsigned int prefix = 0; int kneed = KK;
        for (int r = 0; r < 4; ++r){
            int shift = 24 - 8 * r;
            for (int i = tid; i < 256; i += blockDim.x) hist[i] = 0;
            __syncthreads();
            for (int i = tid; i < n; i += blockDim.x){
                unsigned int bits = __float_as_uint(bs[i]);
                if (r == 0 || (bits >> (shift + 8)) == prefix)
                    atomicAdd(&hist[(bits >> shift) & 255], 1);
            }
            __syncthreads();
            if (tid == 0){
                int cum = 0, d = 255;
                for (; d >= 0; --d){ cum += hist[d]; if (cum >= kneed) break; }
                if (d < 0) d = 0;
                sh_kneed = kneed - (cum - hist[d]);
                sh_prefix = (prefix << 8) | (unsigned int)d;
            }
            __syncthreads();
            prefix = sh_prefix; kneed = sh_kneed;
            __syncthreads();
        }
        Tbits = prefix;
    }

    if (tid == 0) selCnt = 0;
    __syncthreads();
    for (int i = tid; i < n; i += blockDim.x){
        unsigned int bits = __float_as_uint(bs[i]);
        if (bits >= Tbits){
            int p = atomicAdd(&selCnt, 1);
            if (p < SELCAP)
                keys[p] = ((unsigned long long)bits << 32) | (unsigned int)(~bi[i]);
        }
    }
    __syncthreads();
    int ns = selCnt; if (ns > SELCAP) ns = SELCAP;
    int P2 = 2; while (P2 < ns) P2 <<= 1;
    for (int i = tid; i < P2; i += blockDim.x) if (i >= ns) keys[i] = 0ull;
    __syncthreads();

    for (int k = 2; k <= P2; k <<= 1){
        for (int j = k >> 1; j > 0; j >>= 1){
            for (int i = tid; i < P2; i += blockDim.x){
                int partner = i ^ j;
                if (partner > i){
                    unsigned long long a = keys[i], c = keys[partner];
                    bool asc = ((i & k) != 0);
                    if ((a < c) != asc){ keys[i] = c; keys[partner] = a; }
                }
            }
            __syncthreads();
        }
    }

    for (int k = tid; k < KK; k += blockDim.x){
        int idx = -1;
        if (k < ns) idx = (int)(~(unsigned int)(keys[k] & 0xFFFFFFFFull));
        sidx[k] = idx;
    }
    __syncthreads();
    if (ns < KK && tid == 0){
        int fill = ns;
        for (int idx = 0; idx < HWW && fill < KK; ++idx){
            bool inCand = false;
            for (int i = 0; i < n; ++i) if (bi[i] == idx){ inCand = true; break; }
            if (!inCand) sidx[fill++] = idx;
        }
    }
    __syncthreads();

    // outputs: kpts (B,K,4) | feas (B,C,K) | pixels (B,K,2)
    const float* pb = points + (size_t)b * 4 * HWW;
    float* out0 = out + (size_t)b * KK * 4;
    float* out2 = out + (size_t)(BB * KK * 4 + BB * CC * KK) + (size_t)b * KK * 2;
    for (int k = tid; k < KK; k += blockDim.x){
        int idx = sidx[k];
        out0[k * 4 + 0] = pb[idx];
        out0[k * 4 + 1] = pb[HWW + idx];
        out0[k * 4 + 2] = 0.0f;
        out0[k * 4 + 3] = 1.0f;
        out2[k * 2 + 0] = (float)(idx >> 9);
        out2[k * 2 + 1] = (float)(idx & (WW - 1));
    }
    const float* fb = feat + (size_t)b * CC * HWW;
    float* out1 = out + (size_t)(BB * KK * 4) + (size_t)b * CC * KK;
    for (int j = tid; j < CC * KK; j += blockDim.x){
        int c = j >> 9;
        int k = j & (KK - 1);
        out1[c * KK + k] = fb[(size_t)c * HWW + sidx[k]];
    }
}

extern "C" void kernel_launch(void* const* d_in, const int* in_sizes, int n_in,
                              void* d_out, int out_size, void* d_ws, size_t ws_size,
                              hipStream_t stream) {
    const float* s    = (const float*)d_in[0];  // score_bev  (B,1,H,W)
    const float* feat = (const float*)d_in[1];  // feature_bev(B,C,H,W)
    const float* pts  = (const float*)d_in[2];  // points     (B,4,H,W)
    float* out = (float*)d_out;

    char* w = (char*)d_ws;
    float* cs  = (float*)w;  w += (size_t)BB * CAP * 4;
    int*   ci  = (int*)w;    w += (size_t)BB * CAP * 4;
    int*   cnt = (int*)w;    w += 256;

    hipMemsetAsync(cnt, 0, BB * sizeof(int), stream);
    nms_fused_k<<<BB * 64, NT, 0, stream>>>(s, cs, ci, cnt);
    finalize_k<<<BB, 256, 0, stream>>>(cs, ci, cnt, pts, feat, out);
}